// Round 1
// baseline (1082.383 us; speedup 1.0000x reference)
//
#include <hip/hip_runtime.h>
#include <math.h>

// Heat equation: u_{t+1} = u_t + gamma * Lap5(u_t) on interior, 0 on boundary.
// Output: all time_steps frames, f32, [ts, nX, nX].
// Round 0: baseline = 1 init kernel + (ts-1) step kernels, one row per block,
// float4 per thread. Expect launch-overhead dominated (~256 dispatches).

__global__ void heat_init(const float* __restrict__ u0,
                          float* __restrict__ out, int nX) {
    const int row = blockIdx.x;
    const int j   = threadIdx.x;              // float4 index within row
    const int nq  = nX >> 2;
    float4* dst = reinterpret_cast<float4*>(out + (size_t)row * nX);
    if (row == 0 || row == nX - 1) {
        dst[j] = make_float4(0.f, 0.f, 0.f, 0.f);
        return;
    }
    const float4* src = reinterpret_cast<const float4*>(u0 + (size_t)row * nX);
    float4 v = src[j];
    if (j == 0)      v.x = 0.f;
    if (j == nq - 1) v.w = 0.f;
    dst[j] = v;
}

__global__ void heat_step(const float* __restrict__ uin,
                          float* __restrict__ uout,
                          const float* __restrict__ alpha_p,
                          const int* __restrict__ T_p,
                          int nX, int time_steps) {
    const int row = blockIdx.x;
    const int j   = threadIdx.x;
    const int nq  = nX >> 2;
    float4* dst = reinterpret_cast<float4*>(uout + (size_t)row * nX);
    if (row == 0 || row == nX - 1) {
        dst[j] = make_float4(0.f, 0.f, 0.f, 0.f);
        return;
    }
    // gamma from device scalars (uniform; hits L2/L1, negligible)
    const float alpha = *alpha_p;
    const float Tf    = (float)(*T_p);
    const float dx    = 6.0f / (float)(nX - 1);
    const float dt    = Tf / (float)(time_steps - 1);
    const float gamma = alpha * dt / (dx * dx);

    const float*  rowc_s = uin + (size_t)row * nX;
    const float4* rowc = reinterpret_cast<const float4*>(rowc_s);
    const float4* rowu = reinterpret_cast<const float4*>(uin + (size_t)(row - 1) * nX);
    const float4* rowd = reinterpret_cast<const float4*>(uin + (size_t)(row + 1) * nX);

    float4 c  = rowc[j];
    float4 up = rowu[j];
    float4 dn = rowd[j];
    float left  = (j > 0)      ? rowc_s[4 * j - 1] : 0.f;
    float right = (j < nq - 1) ? rowc_s[4 * j + 4] : 0.f;

    float4 r;
    r.x = c.x + gamma * (up.x + dn.x + left + c.y - 4.f * c.x);
    r.y = c.y + gamma * (up.y + dn.y + c.x  + c.z - 4.f * c.y);
    r.z = c.z + gamma * (up.z + dn.z + c.y  + c.w - 4.f * c.z);
    r.w = c.w + gamma * (up.w + dn.w + c.z  + right - 4.f * c.w);

    if (j == 0)      r.x = 0.f;   // column 0 boundary
    if (j == nq - 1) r.w = 0.f;   // column nX-1 boundary
    dst[j] = r;
}

extern "C" void kernel_launch(void* const* d_in, const int* in_sizes, int n_in,
                              void* d_out, int out_size, void* d_ws, size_t ws_size,
                              hipStream_t stream) {
    const float* u0      = (const float*)d_in[0];
    const float* alpha_p = (const float*)d_in[1];
    const int*   T_p     = (const int*)d_in[2];

    const int n0 = in_sizes[0];                       // nX*nX
    int nX = (int)(sqrtf((float)n0) + 0.5f);          // 1024
    const int ts = out_size / n0;                     // 256

    float* out = (float*)d_out;
    const int nq = nX >> 2;                           // 256 threads/row

    heat_init<<<nX, nq, 0, stream>>>(u0, out, nX);
    for (int t = 1; t < ts; ++t) {
        heat_step<<<nX, nq, 0, stream>>>(out + (size_t)(t - 1) * n0,
                                         out + (size_t)t * n0,
                                         alpha_p, T_p, nX, ts);
    }
}

// Round 2
// 852.877 us; speedup vs baseline: 1.2691x; 1.2691x over previous
//
#include <hip/hip_runtime.h>
#include <math.h>

// Heat equation, temporally-blocked: fuse K=8 steps per launch.
// Each block: 64x64 core + halo 8 -> 80x80 LDS tile, double buffered.
// Validity shrinks 1 ring/step: after 8 steps core [8,72) is still exact.

#define CORE 64
#define HALO 8
#define REG  80            // CORE + 2*HALO
#define NQ   (REG / 4)     // 20 float4 per LDS row
#define CQ   (CORE / 4)    // 16 float4 per core row

__global__ __launch_bounds__(256)
void heat_init(const float* __restrict__ u0, float* __restrict__ out, int nX) {
    const int row = blockIdx.x;
    const int j   = threadIdx.x;
    const int nq  = nX >> 2;
    float4* dst = reinterpret_cast<float4*>(out + (size_t)row * nX);
    if (row == 0 || row == nX - 1) {
        dst[j] = make_float4(0.f, 0.f, 0.f, 0.f);
        return;
    }
    const float4* src = reinterpret_cast<const float4*>(u0 + (size_t)row * nX);
    float4 v = src[j];
    if (j == 0)      v.x = 0.f;
    if (j == nq - 1) v.w = 0.f;
    dst[j] = v;
}

__global__ __launch_bounds__(256)
void heat_fused(const float* __restrict__ uin,       // frame t_base
                float* __restrict__ out,             // full output base
                int t_base, int k, int nX, int time_steps,
                const float* __restrict__ alpha_p,
                const int* __restrict__ T_p) {
    __shared__ float buf[2][REG * REG];

    const int tid = threadIdx.x;
    const int gb  = nX / CORE;                 // blocks per dim (16)
    const int bx  = blockIdx.x % gb;
    const int by  = blockIdx.x / gb;
    const int o_r = by * CORE - HALO;
    const int o_c = bx * CORE - HALO;

    const float alpha = *alpha_p;
    const float Tf    = (float)(*T_p);
    const float dx    = 6.0f / (float)(nX - 1);
    const float dt    = Tf / (float)(time_steps - 1);
    const float gamma = alpha * dt / (dx * dx);

    // ---- load 80x80 tile of frame t_base (out-of-domain -> 0) ----
    for (int idx = tid; idx < REG * REG; idx += 256) {
        const int r  = idx / REG, c = idx % REG;
        const int gr = o_r + r,  gc = o_c + c;
        float v = 0.f;
        if (gr >= 0 && gr < nX && gc >= 0 && gc < nX)
            v = uin[(size_t)gr * nX + gc];
        buf[0][idx] = v;
    }
    __syncthreads();

    int cur = 0;
    for (int s = 0; s < k; ++s) {
        const float* __restrict__ bc = buf[cur];
        float*       __restrict__ bn = buf[cur ^ 1];

        // ---- one stencil step on fixed interior rows/cols of the tile ----
        // 78 rows x 20 quads; edge quads read in-bounds garbage, provably
        // outside the validity window -> never consumed by correct points.
        for (int it = tid; it < 78 * NQ; it += 256) {
            const int r = 1 + it / NQ;
            const int q = it % NQ;
            const float4 c4 = reinterpret_cast<const float4*>(bc)[r * NQ + q];
            const float4 u4 = reinterpret_cast<const float4*>(bc)[(r - 1) * NQ + q];
            const float4 d4 = reinterpret_cast<const float4*>(bc)[(r + 1) * NQ + q];
            const float lf = bc[r * REG + 4 * q - 1];
            const float rt = bc[r * REG + 4 * q + 4];

            float4 o;
            o.x = c4.x + gamma * (u4.x + d4.x + lf   + c4.y - 4.f * c4.x);
            o.y = c4.y + gamma * (u4.y + d4.y + c4.x + c4.z - 4.f * c4.y);
            o.z = c4.z + gamma * (u4.z + d4.z + c4.y + c4.w - 4.f * c4.z);
            o.w = c4.w + gamma * (u4.w + d4.w + c4.z + rt   - 4.f * c4.w);

            const int gr  = o_r + r;
            const int gc0 = o_c + 4 * q;
            if (gr <= 0 || gr >= nX - 1) {
                o = make_float4(0.f, 0.f, 0.f, 0.f);
            } else {
                if (gc0     <= 0 || gc0     >= nX - 1) o.x = 0.f;
                if (gc0 + 1 <= 0 || gc0 + 1 >= nX - 1) o.y = 0.f;
                if (gc0 + 2 <= 0 || gc0 + 2 >= nX - 1) o.z = 0.f;
                if (gc0 + 3 <= 0 || gc0 + 3 >= nX - 1) o.w = 0.f;
            }
            reinterpret_cast<float4*>(bn)[r * NQ + q] = o;
        }
        __syncthreads();

        // ---- stream this step's core (64x64) to frame t_base+s+1 ----
        float* of = out + (size_t)(t_base + s + 1) * nX * nX;
        for (int w = tid; w < CORE * CQ; w += 256) {
            const int r = HALO + w / CQ;
            const int q = w % CQ;
            const float4 v = reinterpret_cast<const float4*>(bn)[r * NQ + HALO / 4 + q];
            const int gr = o_r + r;
            const int gc = o_c + HALO + 4 * q;
            *reinterpret_cast<float4*>(of + (size_t)gr * nX + gc) = v;
        }
        cur ^= 1;
        // no second barrier needed: next step writes the buffer no thread
        // reads in this write phase (old bc), and reads bn (already synced).
    }
}

extern "C" void kernel_launch(void* const* d_in, const int* in_sizes, int n_in,
                              void* d_out, int out_size, void* d_ws, size_t ws_size,
                              hipStream_t stream) {
    const float* u0      = (const float*)d_in[0];
    const float* alpha_p = (const float*)d_in[1];
    const int*   T_p     = (const int*)d_in[2];

    const int n0 = in_sizes[0];                   // nX*nX
    const int nX = (int)(sqrtf((float)n0) + 0.5f);
    const int ts = out_size / n0;                 // time_steps

    float* out = (float*)d_out;
    const int gb = nX / CORE;                     // 16
    const int nblocks = gb * gb;                  // 256

    heat_init<<<nX, nX / 4, 0, stream>>>(u0, out, nX);

    for (int t = 0; t < ts - 1; t += HALO) {
        const int k = min(HALO, ts - 1 - t);
        heat_fused<<<nblocks, 256, 0, stream>>>(out + (size_t)t * n0, out,
                                                t, k, nX, ts, alpha_p, T_p);
    }
}

// Round 3
// 481.834 us; speedup vs baseline: 2.2464x; 1.7701x over previous
//
#include <hip/hip_runtime.h>
#include <math.h>

// Heat equation, temporally-blocked: fuse K=16 steps per launch.
// Each block: 64x64 core + halo 16 -> 96x96 LDS tile, double buffered
// (73.7 KB LDS), 1024 threads (16 waves/CU) to hide LDS latency.
// Validity shrinks 1 ring/step: after 16 steps core [16,80) is exact.

#define CORE 64
#define HALO 16
#define REG  96            // CORE + 2*HALO
#define NQ   (REG / 4)     // 24 float4 per LDS row
#define CQ   (CORE / 4)    // 16 float4 per core row
#define TPB  1024

__global__ __launch_bounds__(256)
void heat_init(const float* __restrict__ u0, float* __restrict__ out, int nX) {
    const int row = blockIdx.x;
    const int j   = threadIdx.x;
    const int nq  = nX >> 2;
    float4* dst = reinterpret_cast<float4*>(out + (size_t)row * nX);
    if (row == 0 || row == nX - 1) {
        dst[j] = make_float4(0.f, 0.f, 0.f, 0.f);
        return;
    }
    const float4* src = reinterpret_cast<const float4*>(u0 + (size_t)row * nX);
    float4 v = src[j];
    if (j == 0)      v.x = 0.f;
    if (j == nq - 1) v.w = 0.f;
    dst[j] = v;
}

__global__ __launch_bounds__(TPB)
void heat_fused(const float* __restrict__ uin,       // frame t_base
                float* __restrict__ out,             // full output base
                int t_base, int k, int nX, int time_steps,
                const float* __restrict__ alpha_p,
                const int* __restrict__ T_p) {
    __shared__ float buf[2][REG * REG];

    const int tid = threadIdx.x;
    const int gb  = nX / CORE;                 // 16
    const int bx  = blockIdx.x % gb;
    const int by  = blockIdx.x / gb;
    const int o_r = by * CORE - HALO;
    const int o_c = bx * CORE - HALO;

    const float alpha = *alpha_p;
    const float Tf    = (float)(*T_p);
    const float dx    = 6.0f / (float)(nX - 1);
    const float dt    = Tf / (float)(time_steps - 1);
    const float gamma = alpha * dt / (dx * dx);

    // ---- load 96x96 tile of frame t_base (out-of-domain -> 0) ----
    for (int idx = tid; idx < REG * REG; idx += TPB) {
        const int r  = idx / REG, c = idx % REG;
        const int gr = o_r + r,  gc = o_c + c;
        float v = 0.f;
        if (gr >= 0 && gr < nX && gc >= 0 && gc < nX)
            v = uin[(size_t)gr * nX + gc];
        buf[0][idx] = v;
    }
    __syncthreads();

    int cur = 0;
    for (int s = 0; s < k; ++s) {
        const float* __restrict__ bc = buf[cur];
        float*       __restrict__ bn = buf[cur ^ 1];

        // ---- one stencil step: 94 rows x 24 quads of the tile interior.
        // Edge quads read in-bounds garbage that lies outside the validity
        // window; such points are never consumed by valid core points.
        for (int it = tid; it < 94 * NQ; it += TPB) {
            const int r = 1 + it / NQ;
            const int q = it % NQ;
            const float4 c4 = reinterpret_cast<const float4*>(bc)[r * NQ + q];
            const float4 u4 = reinterpret_cast<const float4*>(bc)[(r - 1) * NQ + q];
            const float4 d4 = reinterpret_cast<const float4*>(bc)[(r + 1) * NQ + q];
            const float lf = bc[r * REG + 4 * q - 1];
            const float rt = bc[r * REG + 4 * q + 4];

            float4 o;
            o.x = c4.x + gamma * (u4.x + d4.x + lf   + c4.y - 4.f * c4.x);
            o.y = c4.y + gamma * (u4.y + d4.y + c4.x + c4.z - 4.f * c4.y);
            o.z = c4.z + gamma * (u4.z + d4.z + c4.y + c4.w - 4.f * c4.z);
            o.w = c4.w + gamma * (u4.w + d4.w + c4.z + rt   - 4.f * c4.w);

            const int gr  = o_r + r;
            const int gc0 = o_c + 4 * q;
            if (gr <= 0 || gr >= nX - 1) {
                o = make_float4(0.f, 0.f, 0.f, 0.f);
            } else {
                if (gc0     <= 0 || gc0     >= nX - 1) o.x = 0.f;
                if (gc0 + 1 <= 0 || gc0 + 1 >= nX - 1) o.y = 0.f;
                if (gc0 + 2 <= 0 || gc0 + 2 >= nX - 1) o.z = 0.f;
                if (gc0 + 3 <= 0 || gc0 + 3 >= nX - 1) o.w = 0.f;
            }
            reinterpret_cast<float4*>(bn)[r * NQ + q] = o;
        }
        __syncthreads();

        // ---- stream this step's core (64x64 = 1024 float4s) to global ----
        float* of = out + (size_t)(t_base + s + 1) * nX * nX;
        {
            const int w = tid;                 // exactly one quad per thread
            const int r = HALO + (w >> 4);
            const int q = w & 15;
            const float4 v = reinterpret_cast<const float4*>(bn)[r * NQ + (HALO / 4) + q];
            const int gr = o_r + r;
            const int gc = o_c + HALO + 4 * q;
            *reinterpret_cast<float4*>(of + (size_t)gr * nX + gc) = v;
        }
        cur ^= 1;
        // single barrier per step is sufficient: the write phase reads bn,
        // the next compute writes old bc (disjoint) and reads bn (synced).
    }
}

extern "C" void kernel_launch(void* const* d_in, const int* in_sizes, int n_in,
                              void* d_out, int out_size, void* d_ws, size_t ws_size,
                              hipStream_t stream) {
    const float* u0      = (const float*)d_in[0];
    const float* alpha_p = (const float*)d_in[1];
    const int*   T_p     = (const int*)d_in[2];

    const int n0 = in_sizes[0];                   // nX*nX
    const int nX = (int)(sqrtf((float)n0) + 0.5f);
    const int ts = out_size / n0;                 // time_steps

    float* out = (float*)d_out;
    const int gb = nX / CORE;                     // 16
    const int nblocks = gb * gb;                  // 256

    heat_init<<<nX, nX / 4, 0, stream>>>(u0, out, nX);

    for (int t = 0; t < ts - 1; t += HALO) {
        const int k = min(HALO, ts - 1 - t);
        heat_fused<<<nblocks, TPB, 0, stream>>>(out + (size_t)t * n0, out,
                                                t, k, nX, ts, alpha_p, T_p);
    }
}

// Round 4
// 330.495 us; speedup vs baseline: 3.2750x; 1.4579x over previous
//
#include <hip/hip_runtime.h>
#include <math.h>

// Heat equation, temporally blocked, K=16 steps/launch.
// Block: 64x64 core + 16 halo -> 96x96 LDS tile, double buffered (73.7 KB),
// 1024 threads. Round 4 changes:
//  - raw s_barrier + lgkmcnt(0) only (no vmcnt drain) -> global frame stores
//    stay in flight across steps and overlap with LDS compute
//  - direct register->global store of core quads (no LDS re-read write phase)
//  - center value carried in registers across steps (stable it->quad mapping)

#define CORE 64
#define HALO 16
#define REG  96            // CORE + 2*HALO
#define NQ   (REG / 4)     // 24 float4 per tile row
#define TPB  1024
#define NIT  (94 * NQ)     // 2256 quads computed per step

__global__ __launch_bounds__(256)
void heat_init(const float* __restrict__ u0, float* __restrict__ out, int nX) {
    const int row = blockIdx.x;
    const int j   = threadIdx.x;
    const int nq  = nX >> 2;
    float4* dst = reinterpret_cast<float4*>(out + (size_t)row * nX);
    if (row == 0 || row == nX - 1) {
        dst[j] = make_float4(0.f, 0.f, 0.f, 0.f);
        return;
    }
    const float4* src = reinterpret_cast<const float4*>(u0 + (size_t)row * nX);
    float4 v = src[j];
    if (j == 0)      v.x = 0.f;
    if (j == nq - 1) v.w = 0.f;
    dst[j] = v;
}

__device__ __forceinline__ void step_quad(const float* __restrict__ bc,
                                          float* __restrict__ bn,
                                          float* __restrict__ of,
                                          int it, float4& c, float gamma,
                                          int o_r, int o_c, int nX) {
    const int r = 1 + it / NQ;
    const int q = it % NQ;
    const float4 u4 = reinterpret_cast<const float4*>(bc)[(r - 1) * NQ + q];
    const float4 d4 = reinterpret_cast<const float4*>(bc)[(r + 1) * NQ + q];
    const float lf = bc[r * REG + 4 * q - 1];
    const float rt = bc[r * REG + 4 * q + 4];

    float4 o;
    o.x = c.x + gamma * (u4.x + d4.x + lf  + c.y - 4.f * c.x);
    o.y = c.y + gamma * (u4.y + d4.y + c.x + c.z - 4.f * c.y);
    o.z = c.z + gamma * (u4.z + d4.z + c.y + c.w - 4.f * c.z);
    o.w = c.w + gamma * (u4.w + d4.w + c.z + rt  - 4.f * c.w);

    const int gr  = o_r + r;
    const int gc0 = o_c + 4 * q;
    if (gr <= 0 || gr >= nX - 1) {
        o = make_float4(0.f, 0.f, 0.f, 0.f);
    } else {
        if (gc0     <= 0 || gc0     >= nX - 1) o.x = 0.f;
        if (gc0 + 1 <= 0 || gc0 + 1 >= nX - 1) o.y = 0.f;
        if (gc0 + 2 <= 0 || gc0 + 2 >= nX - 1) o.z = 0.f;
        if (gc0 + 3 <= 0 || gc0 + 3 >= nX - 1) o.w = 0.f;
    }
    reinterpret_cast<float4*>(bn)[r * NQ + q] = o;

    // direct store of core quads (rows [16,80), col-quads [4,20))
    if (r >= HALO && r < HALO + CORE && q >= HALO / 4 && q < (REG - HALO) / 4) {
        *reinterpret_cast<float4*>(of + (size_t)gr * nX + gc0) = o;
    }
    c = o;   // this step's output is next step's center
}

__global__ __launch_bounds__(TPB)
void heat_fused(const float* __restrict__ uin,       // frame t_base
                float* __restrict__ out,             // full output base
                int t_base, int k, int nX, int time_steps,
                const float* __restrict__ alpha_p,
                const int* __restrict__ T_p) {
    __shared__ float buf[2][REG * REG];

    const int tid = threadIdx.x;
    const int gb  = nX / CORE;                 // 16
    const int bx  = blockIdx.x % gb;
    const int by  = blockIdx.x / gb;
    const int o_r = by * CORE - HALO;
    const int o_c = bx * CORE - HALO;

    const float alpha = *alpha_p;
    const float Tf    = (float)(*T_p);
    const float dx    = 6.0f / (float)(nX - 1);
    const float dt    = Tf / (float)(time_steps - 1);
    const float gamma = alpha * dt / (dx * dx);

    // ---- load 96x96 tile of frame t_base (out-of-domain -> 0) ----
    for (int idx = tid; idx < REG * REG; idx += TPB) {
        const int r  = idx / REG, c = idx % REG;
        const int gr = o_r + r,  gc = o_c + c;
        float v = 0.f;
        if (gr >= 0 && gr < nX && gc >= 0 && gc < nX)
            v = uin[(size_t)gr * nX + gc];
        buf[0][idx] = v;
    }
    asm volatile("s_waitcnt lgkmcnt(0)" ::: "memory");
    __builtin_amdgcn_s_barrier();
    __builtin_amdgcn_sched_barrier(0);

    // ---- init center registers (fidx = it + NQ) ----
    float4 c0 = reinterpret_cast<const float4*>(buf[0])[NQ + tid];
    float4 c1 = reinterpret_cast<const float4*>(buf[0])[NQ + tid + TPB];
    const bool has2 = (tid + 2 * TPB) < NIT;
    float4 c2 = make_float4(0.f, 0.f, 0.f, 0.f);
    if (has2) c2 = reinterpret_cast<const float4*>(buf[0])[NQ + tid + 2 * TPB];

    int cur = 0;
    for (int s = 0; s < k; ++s) {
        const float* __restrict__ bc = buf[cur];
        float*       __restrict__ bn = buf[cur ^ 1];
        float* of = out + (size_t)(t_base + s + 1) * nX * nX;

        step_quad(bc, bn, of, tid,           c0, gamma, o_r, o_c, nX);
        step_quad(bc, bn, of, tid + TPB,     c1, gamma, o_r, o_c, nX);
        if (has2)
            step_quad(bc, bn, of, tid + 2 * TPB, c2, gamma, o_r, o_c, nX);

        // LDS-only drain; global stores remain in flight across the barrier
        asm volatile("s_waitcnt lgkmcnt(0)" ::: "memory");
        __builtin_amdgcn_s_barrier();
        __builtin_amdgcn_sched_barrier(0);
        asm volatile("" ::: "memory");
        cur ^= 1;
    }
}

extern "C" void kernel_launch(void* const* d_in, const int* in_sizes, int n_in,
                              void* d_out, int out_size, void* d_ws, size_t ws_size,
                              hipStream_t stream) {
    const float* u0      = (const float*)d_in[0];
    const float* alpha_p = (const float*)d_in[1];
    const int*   T_p     = (const int*)d_in[2];

    const int n0 = in_sizes[0];                   // nX*nX
    const int nX = (int)(sqrtf((float)n0) + 0.5f);
    const int ts = out_size / n0;                 // time_steps

    float* out = (float*)d_out;
    const int gb = nX / CORE;                     // 16
    const int nblocks = gb * gb;                  // 256

    heat_init<<<nX, nX / 4, 0, stream>>>(u0, out, nX);

    for (int t = 0; t < ts - 1; t += HALO) {
        const int k = min(HALO, ts - 1 - t);
        heat_fused<<<nblocks, TPB, 0, stream>>>(out + (size_t)t * n0, out,
                                                t, k, nX, ts, alpha_p, T_p);
    }
}